// Round 1
// 297.768 us; speedup vs baseline: 1.1125x; 1.1125x over previous
//
#include <hip/hip_runtime.h>

// Problem constants (from reference)
#define BOX 120
#define BOX3 (BOX * BOX * BOX)      // 1,728,000
#define NTYPES 11
#define NBATCH 4
#define BT (NBATCH * NTYPES)        // 44
#define MAXA 512
#define NNB 2
#define KCELLS 125                  // (2*NNB+1)^3

// One thread per (bt, atom, k). k innermost => 5 consecutive lanes write 5
// consecutive z-voxels (same or adjacent cache line) -> coalesced atomics.
__global__ __launch_bounds__(256)
void TypedCoords2Volume_scatter(const float* __restrict__ coords,
                                const int* __restrict__ num_atoms,
                                float* __restrict__ out) {
    int idx = blockIdx.x * blockDim.x + threadIdx.x;
    const int total = BT * MAXA * KCELLS;
    if (idx >= total) return;

    int k   = idx % KCELLS;
    int tmp = idx / KCELLS;
    int a   = tmp % MAXA;
    int bt  = tmp / MAXA;

    int na = num_atoms[bt];
    if (a >= na) return;

    // coords layout: [BT, MAXA, 3] interleaved xyz
    const float* p = coords + (size_t)bt * (3 * MAXA) + (size_t)a * 3;
    float px = p[0];
    float py = p[1];
    float pz = p[2];

    int cx = (int)floorf(px);
    int cy = (int)floorf(py);
    int cz = (int)floorf(pz);

    // offs order from meshgrid(r,r,r, indexing="ij").reshape(-1,3):
    // x outermost, z innermost
    int dz = k % 5;
    int t2 = k / 5;
    int dy = t2 % 5;
    int dx = t2 / 5;

    int nx = cx + dx - NNB;
    int ny = cy + dy - NNB;
    int nz = cz + dz - NNB;

    // in-box mask (reference zeroes out-of-box contributions)
    if ((unsigned)nx >= BOX || (unsigned)ny >= BOX || (unsigned)nz >= BOX) return;

    float fx = (float)nx - px;
    float fy = (float)ny - py;
    float fz = (float)nz - pz;
    float r2 = fx * fx + fy * fy + fz * fz;
    float val = __expf(-r2);   // RESOLUTION = 1.0

    size_t off = (size_t)bt * BOX3 + (size_t)((nx * BOX + ny) * BOX + nz);
    atomicAdd(out + off, val);
}

extern "C" void kernel_launch(void* const* d_in, const int* in_sizes, int n_in,
                              void* d_out, int out_size, void* d_ws, size_t ws_size,
                              hipStream_t stream) {
    const float* coords    = (const float*)d_in[0];   // [4, 11, 1536] fp32
    const int*   num_atoms = (const int*)d_in[1];     // [4, 11] int32
    float*       out       = (float*)d_out;           // [4, 11, 120,120,120] fp32

    // Zero the output grid (harness poisons it with 0xAA before every launch).
    // NOTE: out_size is in BYTES (rocprof WRITE_SIZE of the fill == out_size*4
    // previously == 4x the 304 MB output). Memset exactly the output buffer.
    hipMemsetAsync(d_out, 0, (size_t)out_size, stream);

    const int total  = BT * MAXA * KCELLS;            // 2,816,000 threads
    const int block  = 256;
    const int grid   = (total + block - 1) / block;   // 11,000 blocks
    TypedCoords2Volume_scatter<<<grid, block, 0, stream>>>(coords, num_atoms, out);
}